// Round 4
// baseline (164.105 us; speedup 1.0000x reference)
//
#include <hip/hip_runtime.h>

// rosa_4bit_layer: causal linear attention, per-head 4x4 state.
//   S_t = S_{t-1} + k_t v_t^T ;  o_t = q_t^T S_t ;  out = o * emb
// x{q,k,v}: (B=4, T=4096, C=512) fp32; emb broadcast (512).
// H=128 heads of dim 4, contiguous in C.
//
// Round-3 post-mortem: 3-kernel version ran 151 us; top-5 dispatches were all
// 41-us harness fills => each of our kernels <41 us. k_scan (16 blocks,
// 128 serially-dependent in-place load->add->store iters) was a latency chain
// (~30-50 us for 8 MiB). This round: 2 kernels, scan folded into the output
// kernel as a redundant per-block prefix sum over L2-resident partials
// (independent coalesced loads -> pipelined, no dependency chain).

constexpr int B  = 4;
constexpr int T  = 4096;
constexpr int C  = 512;
constexpr int CT = 32;     // timesteps per chunk
constexpr int NC = T / CT; // 128 chunks
// partials: ((b*NC + c)*128 + h)*16 + e*4 + d  -> 4 MiB in d_ws

__global__ __launch_bounds__(512) void rosa_partial(const float* __restrict__ k,
                                                    const float* __restrict__ v,
                                                    float* __restrict__ part) {
  const int bc  = blockIdx.x;            // b*NC + c
  const int b   = bc / NC;
  const int c   = bc % NC;
  const int tid = threadIdx.x;           // 0..511
  const int h   = tid >> 2;
  const int e   = tid & 3;

  const size_t base = ((size_t)b * T + (size_t)c * CT) * (size_t)C + (h << 2);
  const float* kb = k + base;
  const float* vb = v + base + e;

  float4 acc = {0.f, 0.f, 0.f, 0.f};
#pragma unroll 8
  for (int t = 0; t < CT; ++t) {
    const float4 k4 = *reinterpret_cast<const float4*>(kb + (size_t)t * C);
    const float  ve = vb[(size_t)t * C];
    acc.x += k4.x * ve;
    acc.y += k4.y * ve;
    acc.z += k4.z * ve;
    acc.w += k4.w * ve;
  }
  reinterpret_cast<float4*>(part)[(size_t)bc * 512 + tid] = acc;
}

__global__ __launch_bounds__(512) void rosa_scan_out(const float* __restrict__ q,
                                                     const float* __restrict__ k,
                                                     const float* __restrict__ v,
                                                     const float* __restrict__ emb,
                                                     const float* __restrict__ part,
                                                     float* __restrict__ out) {
  const int bc  = blockIdx.x;
  const int b   = bc / NC;
  const int c   = bc % NC;
  const int tid = threadIdx.x;
  const int h   = tid >> 2;
  const int e   = tid & 3;

  // --- exclusive prefix: sum partials of chunks 0..c-1 (redundant per block).
  // Loads are independent + coalesced (1 KiB/wave); part is 4 MiB -> L2-hot.
  float4 S = {0.f, 0.f, 0.f, 0.f};
  const float4* pb = reinterpret_cast<const float4*>(part) + (size_t)b * NC * 512 + tid;
#pragma unroll 4
  for (int cp = 0; cp < c; ++cp) {
    const float4 p4 = pb[(size_t)cp * 512];
    S.x += p4.x;
    S.y += p4.y;
    S.z += p4.z;
    S.w += p4.w;
  }

  // --- replay this chunk from its start state and write output.
  const size_t base = ((size_t)b * T + (size_t)c * CT) * (size_t)C + (h << 2);
  const float* qb = q + base;
  const float* kb = k + base;
  const float* vb = v + base + e;
  float*       ob = out + base + e;
  const float embv = emb[(h << 2) + e];

#pragma unroll 8
  for (int t = 0; t < CT; ++t) {
    const float4 k4 = *reinterpret_cast<const float4*>(kb + (size_t)t * C);
    const float4 q4 = *reinterpret_cast<const float4*>(qb + (size_t)t * C);
    const float  ve = vb[(size_t)t * C];
    S.x += k4.x * ve;
    S.y += k4.y * ve;
    S.z += k4.z * ve;
    S.w += k4.w * ve;
    const float o = q4.x * S.x + q4.y * S.y + q4.z * S.z + q4.w * S.w;
    ob[(size_t)t * C] = o * embv;
  }
}

extern "C" void kernel_launch(void* const* d_in, const int* in_sizes, int n_in,
                              void* d_out, int out_size, void* d_ws, size_t ws_size,
                              hipStream_t stream) {
  const float* xq  = (const float*)d_in[0];
  const float* xk  = (const float*)d_in[1];
  const float* xv  = (const float*)d_in[2];
  const float* emb = (const float*)d_in[3];
  float* out  = (float*)d_out;
  float* part = (float*)d_ws;   // B*NC*2048 floats = 4 MiB

  rosa_partial<<<B * NC, 512, 0, stream>>>(xk, xv, part);
  rosa_scan_out<<<B * NC, 512, 0, stream>>>(xq, xk, xv, emb, part, out);
}

// Round 6
// 151.269 us; speedup vs baseline: 1.0849x; 1.0849x over previous
//
#include <hip/hip_runtime.h>

// rosa_4bit_layer: causal linear attention, per-head 4x4 state.
//   S_t = S_{t-1} + k_t v_t^T ;  o_t = q_t^T S_t ;  out = o * emb
// x{q,k,v}: (B=4, T=4096, C=512) fp32; emb broadcast (512).
//
// R4 post-mortem: scan_out 47.8us @ 26% HBM, VALU 8% -- limiter is the
// ~266 MB of redundant chunk-partial prefix re-reads, which are served by
// L3/fabric (part is written by OTHER XCDs; per-XCD L2 doesn't help).
// R5: hierarchical prefix. Super-partials (16 chunks each) cut redundant
// prefix loads from <=127 to <=22 per block (~45 MB total L3 traffic).
// (R5 bench was a container-acquisition flake; resubmitting unchanged.)

constexpr int B   = 4;
constexpr int T   = 4096;
constexpr int C   = 512;
constexpr int CT  = 32;       // timesteps per chunk
constexpr int NC  = T / CT;   // 128 chunks
constexpr int SC  = 16;       // chunks per super-chunk
constexpr int NSC = NC / SC;  // 8 super-chunks
// d_ws layout:
//   part : B*NC*2048 floats  (4 MiB)   [(b*NC+c)*2048 + h*16 + e*4 + d]
//   spart: B*NSC*2048 floats (256 KiB) [(b*NSC+s)*2048 + ...] at offset 4 MiB
constexpr size_t SPART_OFF = (size_t)B * NC * 2048;

__global__ __launch_bounds__(512) void rosa_partial(const float* __restrict__ k,
                                                    const float* __restrict__ v,
                                                    float* __restrict__ part) {
  const int bc  = blockIdx.x;            // b*NC + c
  const int b   = bc / NC;
  const int c   = bc % NC;
  const int tid = threadIdx.x;           // 0..511
  const int h   = tid >> 2;
  const int e   = tid & 3;

  const size_t base = ((size_t)b * T + (size_t)c * CT) * (size_t)C + (h << 2);
  const float* kb = k + base;
  const float* vb = v + base + e;

  float4 acc = {0.f, 0.f, 0.f, 0.f};
#pragma unroll 8
  for (int t = 0; t < CT; ++t) {
    const float4 k4 = *reinterpret_cast<const float4*>(kb + (size_t)t * C);
    const float  ve = vb[(size_t)t * C];
    acc.x += k4.x * ve;
    acc.y += k4.y * ve;
    acc.z += k4.z * ve;
    acc.w += k4.w * ve;
  }
  reinterpret_cast<float4*>(part)[(size_t)bc * 512 + tid] = acc;
}

// Sum SC consecutive chunk partials -> one super partial.
// grid: B*NSC*4 blocks of 128 threads; block g-quarter covers 128 float4s.
__global__ __launch_bounds__(128) void rosa_super(const float* __restrict__ part,
                                                  float* __restrict__ spart) {
  const int blk = blockIdx.x;            // ((b*NSC + s)*4 + g)
  const int g   = blk & 3;
  const int bs  = blk >> 2;              // b*NSC + s
  const int b   = bs / NSC;
  const int s   = bs % NSC;
  const int j   = (g << 7) + threadIdx.x;  // float4 index in [0,512)

  const float4* p4 = reinterpret_cast<const float4*>(part) +
                     ((size_t)(b * NC + s * SC)) * 512 + j;
  float4 acc = {0.f, 0.f, 0.f, 0.f};
#pragma unroll
  for (int i = 0; i < SC; ++i) {
    const float4 v4 = p4[(size_t)i * 512];
    acc.x += v4.x;
    acc.y += v4.y;
    acc.z += v4.z;
    acc.w += v4.w;
  }
  reinterpret_cast<float4*>(spart)[(size_t)bs * 512 + j] = acc;
}

__global__ __launch_bounds__(512) void rosa_scan_out(const float* __restrict__ q,
                                                     const float* __restrict__ k,
                                                     const float* __restrict__ v,
                                                     const float* __restrict__ emb,
                                                     const float* __restrict__ part,
                                                     const float* __restrict__ spart,
                                                     float* __restrict__ out) {
  const int bc  = blockIdx.x;
  const int b   = bc / NC;
  const int c   = bc % NC;
  const int tid = threadIdx.x;
  const int h   = tid >> 2;
  const int e   = tid & 3;
  const int s   = c >> 4;                // c / SC
  const int cr  = c & (SC - 1);          // c % SC

  // --- exclusive prefix: supers 0..s-1, then chunks s*SC .. c-1.
  float4 S = {0.f, 0.f, 0.f, 0.f};
  const float4* sp = reinterpret_cast<const float4*>(spart) + (size_t)b * NSC * 512 + tid;
#pragma unroll 4
  for (int i = 0; i < s; ++i) {
    const float4 p4 = sp[(size_t)i * 512];
    S.x += p4.x; S.y += p4.y; S.z += p4.z; S.w += p4.w;
  }
  const float4* pb = reinterpret_cast<const float4*>(part) +
                     ((size_t)(b * NC + s * SC)) * 512 + tid;
#pragma unroll 4
  for (int i = 0; i < cr; ++i) {
    const float4 p4 = pb[(size_t)i * 512];
    S.x += p4.x; S.y += p4.y; S.z += p4.z; S.w += p4.w;
  }

  // --- replay this chunk from its start state and write output.
  const size_t base = ((size_t)b * T + (size_t)c * CT) * (size_t)C + (h << 2);
  const float* qb = q + base;
  const float* kb = k + base;
  const float* vb = v + base + e;
  float*       ob = out + base + e;
  const float embv = emb[(h << 2) + e];

#pragma unroll 8
  for (int t = 0; t < CT; ++t) {
    const float4 k4 = *reinterpret_cast<const float4*>(kb + (size_t)t * C);
    const float4 q4 = *reinterpret_cast<const float4*>(qb + (size_t)t * C);
    const float  ve = vb[(size_t)t * C];
    S.x += k4.x * ve;
    S.y += k4.y * ve;
    S.z += k4.z * ve;
    S.w += k4.w * ve;
    const float o = q4.x * S.x + q4.y * S.y + q4.z * S.z + q4.w * S.w;
    ob[(size_t)t * C] = o * embv;
  }
}

extern "C" void kernel_launch(void* const* d_in, const int* in_sizes, int n_in,
                              void* d_out, int out_size, void* d_ws, size_t ws_size,
                              hipStream_t stream) {
  const float* xq  = (const float*)d_in[0];
  const float* xk  = (const float*)d_in[1];
  const float* xv  = (const float*)d_in[2];
  const float* emb = (const float*)d_in[3];
  float* out   = (float*)d_out;
  float* part  = (float*)d_ws;
  float* spart = part + SPART_OFF;

  rosa_partial<<<B * NC, 512, 0, stream>>>(xk, xv, part);
  rosa_super<<<B * NSC * 4, 128, 0, stream>>>(part, spart);
  rosa_scan_out<<<B * NC, 512, 0, stream>>>(xq, xk, xv, emb, part, spart, out);
}